// Round 15
// baseline (233.282 us; speedup 1.0000x reference)
//
#include <hip/hip_runtime.h>
#include <hip/hip_bf16.h>

// Fused attention: q = (x1@Wq+bq)*log2e/10 (bf16), k = x2@Wk+bk, v = x2@Wv+bv.
// out = normalized exp2(q.k) @ v (offset-free softmax; constant cancels in normalization).
// Row-sum via ones-column d=100. kv split 16-way.
// attn: R12 core (64 q/wave, two-phase counted-vmcnt pipeline) + FUSED merge tail:
// device-scope ticket barrier (all 512 blocks co-resident by __launch_bounds__(256,2)),
// then each block merges its own 16-q-row slice. No separate merge kernel.
// ws: qg 2MB | kg 2MB | vT2 2MB (k-slot permuted) | pacc bf16 26.2MB | lsumg 512KB | ctr 4B

typedef __bf16 bf16x8 __attribute__((ext_vector_type(8)));
typedef float  f32x4  __attribute__((ext_vector_type(4)));
typedef short  short8_t __attribute__((ext_vector_type(8)));

#define SM_C 0.14426950408889634f   /* log2(e) / sqrt(100) */

#if __has_builtin(__builtin_amdgcn_global_load_lds)
#define HAVE_GLL 1
#endif

__device__ __forceinline__ void gload16(const short* g, short* l){
#ifdef HAVE_GLL
  __builtin_amdgcn_global_load_lds(
      (__attribute__((address_space(1))) void*)g,
      (__attribute__((address_space(3))) void*)l,
      16, 0, 0);
#else
  *(short8_t*)(l + (threadIdx.x & 63)*8) = *(const short8_t*)(g);
#endif
}

__device__ __forceinline__ short bf(float f){ return __builtin_bit_cast(short, (__bf16)f); }
__device__ __forceinline__ float bf2f(unsigned short v){
  unsigned u = ((unsigned)v) << 16;
  return __builtin_bit_cast(float, u);
}

#define VMW(n) asm volatile("s_waitcnt vmcnt(" #n ")" ::: "memory")
#define BARC do{ __builtin_amdgcn_s_barrier(); asm volatile("" ::: "memory"); }while(0)

// ---------------- projection kernel: 16 rows/block; q pre-scaled by SM_C ----------------
__global__ __launch_bounds__(256) void proj_qkv(
    const float* __restrict__ x1, const float* __restrict__ x2,
    const float* __restrict__ Wq, const float* __restrict__ bq,
    const float* __restrict__ Wk, const float* __restrict__ bk,
    const float* __restrict__ Wv, const float* __restrict__ bv,
    short* __restrict__ qg, short* __restrict__ kg, short* __restrict__ vT2)
{
  __shared__ float xs[16][128];
  __shared__ float vs[16][104];
  const int z = blockIdx.y;
  const float* x = (z == 0) ? x1 : x2;
  const float* W = (z == 0) ? Wq : (z == 1) ? Wk : Wv;
  const float* b = (z == 0) ? bq : (z == 1) ? bk : bv;
  const int rb = blockIdx.x << 4;            // 16 rows per block
  const int t  = threadIdx.x;
  for (int i = t; i < 2048; i += 256) xs[i >> 7][i & 127] = x[(rb << 7) + i];
  __syncthreads();
  const int rw = t >> 5, cs = t & 31;        // rows rw, rw+8; cols cs*4..cs*4+3
  float4 a0 = make_float4(0.f,0.f,0.f,0.f), a1 = a0;
  if (cs < 25){
    a0 = *(const float4*)(b + (cs << 2)); a1 = a0;
#pragma unroll 8
    for (int i = 0; i < 128; ++i){
      const float4 wv = *(const float4*)(W + i*100 + (cs << 2));
      const float xv0 = xs[rw][i], xv1 = xs[rw+8][i];
      a0.x = fmaf(xv0, wv.x, a0.x); a0.y = fmaf(xv0, wv.y, a0.y);
      a0.z = fmaf(xv0, wv.z, a0.z); a0.w = fmaf(xv0, wv.w, a0.w);
      a1.x = fmaf(xv1, wv.x, a1.x); a1.y = fmaf(xv1, wv.y, a1.y);
      a1.z = fmaf(xv1, wv.z, a1.z); a1.w = fmaf(xv1, wv.w, a1.w);
    }
  }
  if (z < 2){
    if (z == 0){   // fold softmax scale into q: scores come out in log2 units
      a0.x*=SM_C; a0.y*=SM_C; a0.z*=SM_C; a0.w*=SM_C;
      a1.x*=SM_C; a1.y*=SM_C; a1.z*=SM_C; a1.w*=SM_C;
    }
    short* o = (z == 0) ? qg : kg;
    if (cs < 25){
      short4 h0, h1;
      h0.x=bf(a0.x); h0.y=bf(a0.y); h0.z=bf(a0.z); h0.w=bf(a0.w);
      h1.x=bf(a1.x); h1.y=bf(a1.y); h1.z=bf(a1.z); h1.w=bf(a1.w);
      *(short4*)(o + ((rb + rw)     << 7) + (cs << 2)) = h0;
      *(short4*)(o + ((rb + rw + 8) << 7) + (cs << 2)) = h1;
    } else {
      short4 hz; hz.x=0; hz.y=0; hz.z=0; hz.w=0;   // zero-pad cols 100..127
      *(short4*)(o + ((rb + rw)     << 7) + 100 + ((cs - 25) << 2)) = hz;
      *(short4*)(o + ((rb + rw + 8) << 7) + 100 + ((cs - 25) << 2)) = hz;
    }
  } else {
    if (cs < 25){
      vs[rw  ][(cs<<2)+0]=a0.x; vs[rw  ][(cs<<2)+1]=a0.y; vs[rw  ][(cs<<2)+2]=a0.z; vs[rw  ][(cs<<2)+3]=a0.w;
      vs[rw+8][(cs<<2)+0]=a1.x; vs[rw+8][(cs<<2)+1]=a1.y; vs[rw+8][(cs<<2)+2]=a1.z; vs[rw+8][(cs<<2)+3]=a1.w;
    }
    __syncthreads();
    if (t < 128){
      const int d = t;
      // k-slot-permuted layout, 32-periodic: idx = g*8+j <-> kv = 4g + (j<4 ? j : 12+j)
      // d==100 -> ones column (row-sum extraction); d>100 -> zeros
#pragma unroll
      for (int h = 0; h < 4; ++h){
        const int kv0 = rb + h*4;
        const int o32 = kv0 & 31;
        const int idx = (o32 < 16) ? ((o32 >> 2) << 3) : ((((o32 - 16) >> 2) << 3) + 4);
        const int r0 = kv0 - rb;
        short4 hv;
        hv.x = (d<100)? bf(vs[r0+0][d]) : (d==100 ? (short)0x3F80 : (short)0);
        hv.y = (d<100)? bf(vs[r0+1][d]) : (d==100 ? (short)0x3F80 : (short)0);
        hv.z = (d<100)? bf(vs[r0+2][d]) : (d==100 ? (short)0x3F80 : (short)0);
        hv.w = (d<100)? bf(vs[r0+3][d]) : (d==100 ? (short)0x3F80 : (short)0);
        *(short4*)(vT2 + (d << 13) + (kv0 & ~31) + idx) = hv;
      }
    }
  }
}

// ---------------- fused attention + merge: 512 blocks = 32 qtiles x 16 parts ----------------
__global__ __launch_bounds__(256, 2) void attn_fwd(
    const short* __restrict__ qg, const short* __restrict__ kg,
    const short* __restrict__ vT2, short* __restrict__ pacc,
    float* __restrict__ lsumg, unsigned* __restrict__ ctr,
    float* __restrict__ out)
{
  __shared__ alignas(1024) short sK[2][4096];    // 8KB/buf, 16B-block swizzled (XOR r&15)
  __shared__ alignas(1024) short sVT[2][4096];   // 8KB/buf: 64 super-rows (2 d's) x 128B, XOR dd&3
  const int tid  = threadIdx.x;
  const int w    = tid >> 6;
  const int lane = tid & 63;
  const int g    = lane >> 4;
  const int ln   = lane & 15;
  const int orig = blockIdx.x;
  const int part = ((orig & 7) << 1) | ((orig >> 3) & 1);
  const int qt   = orig >> 4;                    // 0..31
  const int qb   = qt*256 + w*64;                // 64 q rows per wave
  const int kvbase = part << 9;                  // 512 kv per part

  // Q fragments (B-operand): lane holds Q[qb+sub*16+ln][ks*32 + g*8 + j], sub=0..3
  bf16x8 qf[4][4];
#pragma unroll
  for (int sub = 0; sub < 4; ++sub)
#pragma unroll
    for (int ks = 0; ks < 4; ++ks)
      qf[sub][ks] = *(const bf16x8*)(qg + (qb + sub*16 + ln)*128 + ks*32 + g*8);

  f32x4 acc[4][7];
#pragma unroll
  for (int sub = 0; sub < 4; ++sub)
#pragma unroll
    for (int db = 0; db < 7; ++db) acc[sub][db] = f32x4{0.f,0.f,0.f,0.f};

  // per-lane staging sources: wave w owns chunks {w, w+4} of K and of V (2+2 loads/tile)
  const short *kA0, *kA1, *vA0, *vA1;
  {
    const int r0 = (w << 2)       + (lane >> 4);
    const int r1 = ((w + 4) << 2) + (lane >> 4);
    kA0 = kg + (kvbase + r0)*128 + (((lane & 15) ^ (r0 & 15)) << 3);
    kA1 = kg + (kvbase + r1)*128 + (((lane & 15) ^ (r1 & 15)) << 3);
    const int a0 = (w << 10) + (lane << 4);
    const int a1 = ((w + 4) << 10) + (lane << 4);
    const int dd0 = a0 >> 7, d0 = (dd0 << 1) + ((a0 >> 6) & 1), gs0 = ((a0 >> 4) & 3) ^ (dd0 & 3);
    const int dd1 = a1 >> 7, d1 = (dd1 << 1) + ((a1 >> 6) & 1), gs1 = ((a1 >> 4) & 3) ^ (dd1 & 3);
    vA0 = vT2 + d0*8192 + kvbase + (gs0 << 3);
    vA1 = vT2 + d1*8192 + kvbase + (gs1 << 3);
  }

  auto stageK = [&](int tt){
    short* dst = sK[tt & 1];
    const int off = tt << 12;                    // 32 kv rows * 128 shorts
    gload16(kA0 + off, dst + (w << 9));
    gload16(kA1 + off, dst + ((w + 4) << 9));
  };
  auto stageV = [&](int tt){
    short* dst = sVT[tt & 1];
    const int off = tt << 5;                     // 32 kv shorts (contiguous kv dim)
    gload16(vA0 + off, dst + (w << 9));
    gload16(vA1 + off, dst + ((w + 4) << 9));
  };

  bf16x8 pb[4];                                  // P fragments, live phaseA -> phaseB

  auto phaseA = [&](int buf, int sv){            // QK^T + exp2 (reads K[buf])
    if (sv >= 0) stageV(sv);
    const short* sKc = sK[buf];
    f32x4 st[4][2];
#pragma unroll
    for (int sub = 0; sub < 4; ++sub){
      st[sub][0] = f32x4{0.f,0.f,0.f,0.f};
      st[sub][1] = f32x4{0.f,0.f,0.f,0.f};
    }
    __builtin_amdgcn_s_setprio(1);
#pragma unroll
    for (int s = 0; s < 2; ++s){
      const int rbase = (s*16 + ln) << 7;
#pragma unroll
      for (int ks = 0; ks < 4; ++ks){
        bf16x8 kf = *(const bf16x8*)(sKc + rbase + ((((ks << 2) + g) ^ ln) << 3));
        st[0][s] = __builtin_amdgcn_mfma_f32_16x16x32_bf16(kf, qf[0][ks], st[0][s], 0, 0, 0);
        st[1][s] = __builtin_amdgcn_mfma_f32_16x16x32_bf16(kf, qf[1][ks], st[1][s], 0, 0, 0);
        st[2][s] = __builtin_amdgcn_mfma_f32_16x16x32_bf16(kf, qf[2][ks], st[2][s], 0, 0, 0);
        st[3][s] = __builtin_amdgcn_mfma_f32_16x16x32_bf16(kf, qf[3][ks], st[3][s], 0, 0, 0);
      }
    }
    __builtin_amdgcn_s_setprio(0);
#pragma unroll
    for (int sub = 0; sub < 4; ++sub){
      bf16x8 pv;
#pragma unroll
      for (int r = 0; r < 4; ++r){
        pv[r]     = (__bf16)exp2f(st[sub][0][r]);  // k-slot j<4  -> kv = 4g+j
        pv[4 + r] = (__bf16)exp2f(st[sub][1][r]);  // k-slot j>=4 -> kv = 16+4g+(j-4)
      }
      pb[sub] = pv;
    }
  };

  auto phaseB = [&](int buf, int sk){            // PV (reads V[buf])
    if (sk >= 0) stageK(sk);
    const short* sVc = sVT[buf];
    __builtin_amdgcn_s_setprio(1);
#pragma unroll
    for (int db = 0; db < 7; ++db){
      const int row = db*16 + ln;
      const int dd  = row >> 1;
      bf16x8 vf = *(const bf16x8*)(sVc + (dd << 6) + ((row & 1) << 5) + ((g ^ (dd & 3)) << 3));
      acc[0][db] = __builtin_amdgcn_mfma_f32_16x16x32_bf16(vf, pb[0], acc[0][db], 0, 0, 0);
      acc[1][db] = __builtin_amdgcn_mfma_f32_16x16x32_bf16(vf, pb[1], acc[1][db], 0, 0, 0);
      acc[2][db] = __builtin_amdgcn_mfma_f32_16x16x32_bf16(vf, pb[2], acc[2][db], 0, 0, 0);
      acc[3][db] = __builtin_amdgcn_mfma_f32_16x16x32_bf16(vf, pb[3], acc[3][db], 0, 0, 0);
    }
    __builtin_amdgcn_s_setprio(0);
  };

  // prologue: 6 loads in flight (K0,V0,K1); R12 schedule (16 tiles)
  stageK(0); stageV(0); stageK(1);
  for (int t = 0; t < 14; ++t){
    VMW(4); BARC; phaseA(t & 1, t + 1);          // K(t) ready; V(t),K(t+1) stay in flight
    VMW(4); BARC; phaseB(t & 1, t + 2);          // V(t) ready; K(t+1),V(t+1) in flight
  }
  VMW(4); BARC; phaseA(0, 15);                   // t=14
  VMW(4); BARC; phaseB(0, -1);
  VMW(2); BARC; phaseA(1, -1);                   // t=15
  VMW(0); BARC; phaseB(1, -1);

  // ---- epilogue: bf16 partials (d<100) + fp32 row-sums from ones-column (d=100) ----
#pragma unroll
  for (int sub = 0; sub < 4; ++sub){
#pragma unroll
    for (int db = 0; db < 7; ++db)
#pragma unroll
      for (int r = 0; r < 4; ++r){
        const int d = db*16 + g*4 + r;
        if (d < 100)
          pacc[((part*100 + d) << 13) + qb + sub*16 + ln] = bf(acc[sub][db][r]);
      }
    if (g == 1)  // acc[sub][6][0] is d = 96+4 = 100 -> row sum
      lsumg[(part << 13) + qb + sub*16 + ln] = acc[sub][6][0];
  }

  // ================= fused merge: ticket barrier, then 16-q-row slice =================
  // All 512 blocks are co-resident (launch_bounds(256,2) => 2 waves/SIMD => 2 blocks/CU,
  // LDS 64KB/CU < 160KB), so spinning is deadlock-free. Bounded spin as a no-hang failsafe.
  __threadfence();                               // release this block's pacc/lsumg stores
  __syncthreads();
  if (tid == 0){
    __hip_atomic_fetch_add(ctr, 1u, __ATOMIC_RELEASE, __HIP_MEMORY_SCOPE_AGENT);
    unsigned v = 0; long it = 0;
    do {
      v = __hip_atomic_load(ctr, __ATOMIC_ACQUIRE, __HIP_MEMORY_SCOPE_AGENT);
    } while (v < 512u && ++it < (1L << 26));
  }
  __syncthreads();
  __threadfence();                               // acquire: see all blocks' stores

  {
    float* linv = (float*)&sK[0][0];             // reuse LDS (16 floats)
    const int q0 = orig << 4;                    // this block merges q rows q0..q0+15
    if (tid < 16){
      float L = 0.f;
#pragma unroll
      for (int p = 0; p < 16; ++p) L += lsumg[(p << 13) + q0 + tid];
      linv[tid] = 1.0f / L;
    }
    __syncthreads();
    if (tid < 200){
      const int d    = tid >> 1;                 // 0..99
      const int half = tid & 1;                  // q octet
      const int q8   = q0 + (half << 3);
      float s8[8];
#pragma unroll
      for (int j = 0; j < 8; ++j) s8[j] = 0.f;
#pragma unroll
      for (int p = 0; p < 16; ++p){
        short8_t v = *(const short8_t*)(pacc + ((p*100 + d) << 13) + q8);
#pragma unroll
        for (int j = 0; j < 8; ++j) s8[j] += bf2f((unsigned short)v[j]);
      }
#pragma unroll
      for (int j = 0; j < 8; ++j)
        out[(q8 + j)*100 + d] = s8[j] * linv[(half << 3) + j];
    }
  }
}

// ---------------- launcher ----------------
extern "C" void kernel_launch(void* const* d_in, const int* in_sizes, int n_in,
                              void* d_out, int out_size, void* d_ws, size_t ws_size,
                              hipStream_t stream)
{
  const float* x1 = (const float*)d_in[0];
  const float* x2 = (const float*)d_in[1];
  const float* Wq = (const float*)d_in[2];
  const float* bq = (const float*)d_in[3];
  const float* Wk = (const float*)d_in[4];
  const float* bk = (const float*)d_in[5];
  const float* Wv = (const float*)d_in[6];
  const float* bv = (const float*)d_in[7];
  char* ws = (char*)d_ws;
  short*    qg    = (short*)ws;                                   // 2 MB
  short*    kg    = (short*)(ws + (1u << 21));                    // 2 MB
  short*    vT2   = (short*)(ws + (2u << 21));                    // 2 MB (k-slot permuted)
  short*    pacc  = (short*)(ws + (3u << 21));                    // 16*100*8192*2 = 26.2 MB
  float*    lsumg = (float*)(ws + (3u << 21) + 26214400u);        // 16*8192*4 = 512 KB
  unsigned* ctr   = (unsigned*)(ws + (3u << 21) + 26214400u + 524288u);
  float*    out   = (float*)d_out;

  hipMemsetAsync(ctr, 0, 4, stream);
  proj_qkv<<<dim3(512, 3), 256, 0, stream>>>(x1, x2, Wq, bq, Wk, bk, Wv, bv, qg, kg, vT2);
  attn_fwd<<<512, 256, 0, stream>>>(qg, kg, vT2, pacc, lsumg, ctr, out);
}

// Round 16
// 77.698 us; speedup vs baseline: 3.0024x; 3.0024x over previous
//
#include <hip/hip_runtime.h>
#include <hip/hip_bf16.h>

// Fused attention: q = (x1@Wq+bq)*log2e/10 (bf16), k = x2@Wk+bk, v = x2@Wv+bv.
// out = normalized exp2(q.k) @ v (offset-free softmax; constant cancels in normalization).
// Row-sum via ones-column d=100. kv split 16-way; merge = plain sums (vectorized).
// attn: R8 two-phase counted-vmcnt pipeline, 64 q rows/wave (qf[4]) -> each
// K/V LDS fragment feeds 4 MFMAs (halves LDS read traffic per unit work).
// 512 blocks = 32 qtiles x 16 parts, 2 blocks/CU.
// ws: qg 2MB | kg 2MB | vT2 2MB (k-slot permuted) | pacc bf16 26.2MB | lsumg 512KB

typedef __bf16 bf16x8 __attribute__((ext_vector_type(8)));
typedef float  f32x4  __attribute__((ext_vector_type(4)));
typedef short  short8_t __attribute__((ext_vector_type(8)));

#define SM_C 0.14426950408889634f   /* log2(e) / sqrt(100) */

#if __has_builtin(__builtin_amdgcn_global_load_lds)
#define HAVE_GLL 1
#endif

__device__ __forceinline__ void gload16(const short* g, short* l){
#ifdef HAVE_GLL
  __builtin_amdgcn_global_load_lds(
      (__attribute__((address_space(1))) void*)g,
      (__attribute__((address_space(3))) void*)l,
      16, 0, 0);
#else
  *(short8_t*)(l + (threadIdx.x & 63)*8) = *(const short8_t*)(g);
#endif
}

__device__ __forceinline__ short bf(float f){ return __builtin_bit_cast(short, (__bf16)f); }
__device__ __forceinline__ float bf2f(unsigned short v){
  unsigned u = ((unsigned)v) << 16;
  return __builtin_bit_cast(float, u);
}

#define VMW(n) asm volatile("s_waitcnt vmcnt(" #n ")" ::: "memory")
#define BARC do{ __builtin_amdgcn_s_barrier(); asm volatile("" ::: "memory"); }while(0)

// ---------------- projection kernel: 16 rows/block; q pre-scaled by SM_C ----------------
__global__ __launch_bounds__(256) void proj_qkv(
    const float* __restrict__ x1, const float* __restrict__ x2,
    const float* __restrict__ Wq, const float* __restrict__ bq,
    const float* __restrict__ Wk, const float* __restrict__ bk,
    const float* __restrict__ Wv, const float* __restrict__ bv,
    short* __restrict__ qg, short* __restrict__ kg, short* __restrict__ vT2)
{
  __shared__ float xs[16][128];
  __shared__ float vs[16][104];
  const int z = blockIdx.y;
  const float* x = (z == 0) ? x1 : x2;
  const float* W = (z == 0) ? Wq : (z == 1) ? Wk : Wv;
  const float* b = (z == 0) ? bq : (z == 1) ? bk : bv;
  const int rb = blockIdx.x << 4;            // 16 rows per block
  const int t  = threadIdx.x;
  for (int i = t; i < 2048; i += 256) xs[i >> 7][i & 127] = x[(rb << 7) + i];
  __syncthreads();
  const int rw = t >> 5, cs = t & 31;        // rows rw, rw+8; cols cs*4..cs*4+3
  float4 a0 = make_float4(0.f,0.f,0.f,0.f), a1 = a0;
  if (cs < 25){
    a0 = *(const float4*)(b + (cs << 2)); a1 = a0;
#pragma unroll 8
    for (int i = 0; i < 128; ++i){
      const float4 wv = *(const float4*)(W + i*100 + (cs << 2));
      const float xv0 = xs[rw][i], xv1 = xs[rw+8][i];
      a0.x = fmaf(xv0, wv.x, a0.x); a0.y = fmaf(xv0, wv.y, a0.y);
      a0.z = fmaf(xv0, wv.z, a0.z); a0.w = fmaf(xv0, wv.w, a0.w);
      a1.x = fmaf(xv1, wv.x, a1.x); a1.y = fmaf(xv1, wv.y, a1.y);
      a1.z = fmaf(xv1, wv.z, a1.z); a1.w = fmaf(xv1, wv.w, a1.w);
    }
  }
  if (z < 2){
    if (z == 0){   // fold softmax scale into q: scores come out in log2 units
      a0.x*=SM_C; a0.y*=SM_C; a0.z*=SM_C; a0.w*=SM_C;
      a1.x*=SM_C; a1.y*=SM_C; a1.z*=SM_C; a1.w*=SM_C;
    }
    short* o = (z == 0) ? qg : kg;
    if (cs < 25){
      short4 h0, h1;
      h0.x=bf(a0.x); h0.y=bf(a0.y); h0.z=bf(a0.z); h0.w=bf(a0.w);
      h1.x=bf(a1.x); h1.y=bf(a1.y); h1.z=bf(a1.z); h1.w=bf(a1.w);
      *(short4*)(o + ((rb + rw)     << 7) + (cs << 2)) = h0;
      *(short4*)(o + ((rb + rw + 8) << 7) + (cs << 2)) = h1;
    } else {
      short4 hz; hz.x=0; hz.y=0; hz.z=0; hz.w=0;   // zero-pad cols 100..127
      *(short4*)(o + ((rb + rw)     << 7) + 100 + ((cs - 25) << 2)) = hz;
      *(short4*)(o + ((rb + rw + 8) << 7) + 100 + ((cs - 25) << 2)) = hz;
    }
  } else {
    if (cs < 25){
      vs[rw  ][(cs<<2)+0]=a0.x; vs[rw  ][(cs<<2)+1]=a0.y; vs[rw  ][(cs<<2)+2]=a0.z; vs[rw  ][(cs<<2)+3]=a0.w;
      vs[rw+8][(cs<<2)+0]=a1.x; vs[rw+8][(cs<<2)+1]=a1.y; vs[rw+8][(cs<<2)+2]=a1.z; vs[rw+8][(cs<<2)+3]=a1.w;
    }
    __syncthreads();
    if (t < 128){
      const int d = t;
      // k-slot-permuted layout, 32-periodic: idx = g*8+j <-> kv = 4g + (j<4 ? j : 12+j)
      // d==100 -> ones column (row-sum extraction); d>100 -> zeros
#pragma unroll
      for (int h = 0; h < 4; ++h){
        const int kv0 = rb + h*4;
        const int o32 = kv0 & 31;
        const int idx = (o32 < 16) ? ((o32 >> 2) << 3) : ((((o32 - 16) >> 2) << 3) + 4);
        const int r0 = kv0 - rb;
        short4 hv;
        hv.x = (d<100)? bf(vs[r0+0][d]) : (d==100 ? (short)0x3F80 : (short)0);
        hv.y = (d<100)? bf(vs[r0+1][d]) : (d==100 ? (short)0x3F80 : (short)0);
        hv.z = (d<100)? bf(vs[r0+2][d]) : (d==100 ? (short)0x3F80 : (short)0);
        hv.w = (d<100)? bf(vs[r0+3][d]) : (d==100 ? (short)0x3F80 : (short)0);
        *(short4*)(vT2 + (d << 13) + (kv0 & ~31) + idx) = hv;
      }
    }
  }
}

// ---------------- flash attention: 512 blocks = 32 qtiles x 16 parts, 64 q/wave ----------------
__global__ __launch_bounds__(256, 2) void attn_fwd(
    const short* __restrict__ qg, const short* __restrict__ kg,
    const short* __restrict__ vT2, short* __restrict__ pacc,
    float* __restrict__ lsumg)
{
  __shared__ alignas(1024) short sK[2][4096];    // 8KB/buf, 16B-block swizzled (XOR r&15)
  __shared__ alignas(1024) short sVT[2][4096];   // 8KB/buf: 64 super-rows (2 d's) x 128B, XOR dd&3
  const int tid  = threadIdx.x;
  const int w    = tid >> 6;
  const int lane = tid & 63;
  const int g    = lane >> 4;
  const int ln   = lane & 15;
  const int orig = blockIdx.x;
  const int part = ((orig & 7) << 1) | ((orig >> 3) & 1);
  const int qt   = orig >> 4;                    // 0..31
  const int qb   = qt*256 + w*64;                // 64 q rows per wave
  const int kvbase = part << 9;                  // 512 kv per part

  // Q fragments (B-operand): lane holds Q[qb+sub*16+ln][ks*32 + g*8 + j], sub=0..3
  bf16x8 qf[4][4];
#pragma unroll
  for (int sub = 0; sub < 4; ++sub)
#pragma unroll
    for (int ks = 0; ks < 4; ++ks)
      qf[sub][ks] = *(const bf16x8*)(qg + (qb + sub*16 + ln)*128 + ks*32 + g*8);

  f32x4 acc[4][7];
#pragma unroll
  for (int sub = 0; sub < 4; ++sub)
#pragma unroll
    for (int db = 0; db < 7; ++db) acc[sub][db] = f32x4{0.f,0.f,0.f,0.f};

  // per-lane staging sources: wave w owns chunks {w, w+4} of K and of V (2+2 loads/tile)
  const short *kA0, *kA1, *vA0, *vA1;
  {
    const int r0 = (w << 2)       + (lane >> 4);
    const int r1 = ((w + 4) << 2) + (lane >> 4);
    kA0 = kg + (kvbase + r0)*128 + (((lane & 15) ^ (r0 & 15)) << 3);
    kA1 = kg + (kvbase + r1)*128 + (((lane & 15) ^ (r1 & 15)) << 3);
    const int a0 = (w << 10) + (lane << 4);
    const int a1 = ((w + 4) << 10) + (lane << 4);
    const int dd0 = a0 >> 7, d0 = (dd0 << 1) + ((a0 >> 6) & 1), gs0 = ((a0 >> 4) & 3) ^ (dd0 & 3);
    const int dd1 = a1 >> 7, d1 = (dd1 << 1) + ((a1 >> 6) & 1), gs1 = ((a1 >> 4) & 3) ^ (dd1 & 3);
    vA0 = vT2 + d0*8192 + kvbase + (gs0 << 3);
    vA1 = vT2 + d1*8192 + kvbase + (gs1 << 3);
  }

  auto stageK = [&](int tt){
    short* dst = sK[tt & 1];
    const int off = tt << 12;                    // 32 kv rows * 128 shorts
    gload16(kA0 + off, dst + (w << 9));
    gload16(kA1 + off, dst + ((w + 4) << 9));
  };
  auto stageV = [&](int tt){
    short* dst = sVT[tt & 1];
    const int off = tt << 5;                     // 32 kv shorts (contiguous kv dim)
    gload16(vA0 + off, dst + (w << 9));
    gload16(vA1 + off, dst + ((w + 4) << 9));
  };

  bf16x8 pb[4];                                  // P fragments, live phaseA -> phaseB

  auto phaseA = [&](int buf, int sv){            // QK^T + exp2 (reads K[buf])
    if (sv >= 0) stageV(sv);
    const short* sKc = sK[buf];
    f32x4 st[4][2];
#pragma unroll
    for (int sub = 0; sub < 4; ++sub){
      st[sub][0] = f32x4{0.f,0.f,0.f,0.f};
      st[sub][1] = f32x4{0.f,0.f,0.f,0.f};
    }
    __builtin_amdgcn_s_setprio(1);
#pragma unroll
    for (int s = 0; s < 2; ++s){
      const int rbase = (s*16 + ln) << 7;
#pragma unroll
      for (int ks = 0; ks < 4; ++ks){
        bf16x8 kf = *(const bf16x8*)(sKc + rbase + ((((ks << 2) + g) ^ ln) << 3));
        st[0][s] = __builtin_amdgcn_mfma_f32_16x16x32_bf16(kf, qf[0][ks], st[0][s], 0, 0, 0);
        st[1][s] = __builtin_amdgcn_mfma_f32_16x16x32_bf16(kf, qf[1][ks], st[1][s], 0, 0, 0);
        st[2][s] = __builtin_amdgcn_mfma_f32_16x16x32_bf16(kf, qf[2][ks], st[2][s], 0, 0, 0);
        st[3][s] = __builtin_amdgcn_mfma_f32_16x16x32_bf16(kf, qf[3][ks], st[3][s], 0, 0, 0);
      }
    }
    __builtin_amdgcn_s_setprio(0);
#pragma unroll
    for (int sub = 0; sub < 4; ++sub){
      bf16x8 pv;
#pragma unroll
      for (int r = 0; r < 4; ++r){
        pv[r]     = (__bf16)exp2f(st[sub][0][r]);  // k-slot j<4  -> kv = 4g+j
        pv[4 + r] = (__bf16)exp2f(st[sub][1][r]);  // k-slot j>=4 -> kv = 16+4g+(j-4)
      }
      pb[sub] = pv;
    }
  };

  auto phaseB = [&](int buf, int sk){            // PV (reads V[buf])
    if (sk >= 0) stageK(sk);
    const short* sVc = sVT[buf];
    __builtin_amdgcn_s_setprio(1);
#pragma unroll
    for (int db = 0; db < 7; ++db){
      const int row = db*16 + ln;
      const int dd  = row >> 1;
      bf16x8 vf = *(const bf16x8*)(sVc + (dd << 6) + ((row & 1) << 5) + ((g ^ (dd & 3)) << 3));
      acc[0][db] = __builtin_amdgcn_mfma_f32_16x16x32_bf16(vf, pb[0], acc[0][db], 0, 0, 0);
      acc[1][db] = __builtin_amdgcn_mfma_f32_16x16x32_bf16(vf, pb[1], acc[1][db], 0, 0, 0);
      acc[2][db] = __builtin_amdgcn_mfma_f32_16x16x32_bf16(vf, pb[2], acc[2][db], 0, 0, 0);
      acc[3][db] = __builtin_amdgcn_mfma_f32_16x16x32_bf16(vf, pb[3], acc[3][db], 0, 0, 0);
    }
    __builtin_amdgcn_s_setprio(0);
  };

  // prologue: 6 loads in flight (K0,V0,K1); R8 schedule
  stageK(0); stageV(0); stageK(1);
  for (int t = 0; t < 14; ++t){
    VMW(4); BARC; phaseA(t & 1, t + 1);          // K(t) ready; V(t),K(t+1) stay in flight
    VMW(4); BARC; phaseB(t & 1, t + 2);          // V(t) ready; K(t+1),V(t+1) in flight
  }
  VMW(4); BARC; phaseA(0, 15);                   // t=14
  VMW(4); BARC; phaseB(0, -1);
  VMW(2); BARC; phaseA(1, -1);                   // t=15
  VMW(0); BARC; phaseB(1, -1);

  // ---- epilogue: bf16 partials (d<100) + fp32 row-sums from ones-column (d=100) ----
#pragma unroll
  for (int sub = 0; sub < 4; ++sub){
#pragma unroll
    for (int db = 0; db < 7; ++db)
#pragma unroll
      for (int r = 0; r < 4; ++r){
        const int d = db*16 + g*4 + r;
        if (d < 100)
          pacc[((part*100 + d) << 13) + qb + sub*16 + ln] = bf(acc[sub][db][r]);
      }
    if (g == 1)  // acc[sub][6][0] is d = 96+4 = 100 -> row sum
      lsumg[(part << 13) + qb + sub*16 + ln] = acc[sub][6][0];
  }
}

// ---------------- merge kernel: 512 blocks (128 q-blocks x 4 d-chunks), short8 loads ----------------
__global__ __launch_bounds__(256) void merge_parts(
    const short* __restrict__ pacc, const float* __restrict__ lsumg,
    float* __restrict__ out)
{
  __shared__ float ol[64][26];
  const int t   = threadIdx.x;
  const int qo8 = (t & 7) << 3;          // q octet offset 0..56
  const int dt  = t >> 3;                // 0..31 (25 used)
  const int qb  = blockIdx.x << 6;       // 64 q rows
  const int db  = blockIdx.y * 25;       // 25 d cols
  const int q0  = qb + qo8;

  // row sums for this thread's 8 q's (same for all dt -> L1 broadcast)
  float L8[8];
#pragma unroll
  for (int j = 0; j < 8; ++j) L8[j] = 0.f;
#pragma unroll
  for (int p = 0; p < 16; ++p){
    const float4 a = *(const float4*)(lsumg + (p << 13) + q0);
    const float4 c = *(const float4*)(lsumg + (p << 13) + q0 + 4);
    L8[0]+=a.x; L8[1]+=a.y; L8[2]+=a.z; L8[3]+=a.w;
    L8[4]+=c.x; L8[5]+=c.y; L8[6]+=c.z; L8[7]+=c.w;
  }

  if (dt < 25){
    const int d = db + dt;
    float s8[8];
#pragma unroll
    for (int j = 0; j < 8; ++j) s8[j] = 0.f;
#pragma unroll
    for (int p = 0; p < 16; ++p){
      short8_t v = *(const short8_t*)(pacc + ((p*100 + d) << 13) + q0);
#pragma unroll
      for (int j = 0; j < 8; ++j) s8[j] += bf2f((unsigned short)v[j]);
    }
#pragma unroll
    for (int j = 0; j < 8; ++j) ol[qo8 + j][dt] = s8[j] / L8[j];
  }
  __syncthreads();
  for (int idx = t; idx < 1600; idx += 256){
    const int q2 = idx / 25, d2 = idx - q2*25;
    out[(qb + q2)*100 + db + d2] = ol[q2][d2];
  }
}

// ---------------- launcher ----------------
extern "C" void kernel_launch(void* const* d_in, const int* in_sizes, int n_in,
                              void* d_out, int out_size, void* d_ws, size_t ws_size,
                              hipStream_t stream)
{
  const float* x1 = (const float*)d_in[0];
  const float* x2 = (const float*)d_in[1];
  const float* Wq = (const float*)d_in[2];
  const float* bq = (const float*)d_in[3];
  const float* Wk = (const float*)d_in[4];
  const float* bk = (const float*)d_in[5];
  const float* Wv = (const float*)d_in[6];
  const float* bv = (const float*)d_in[7];
  char* ws = (char*)d_ws;
  short* qg    = (short*)ws;                                   // 2 MB
  short* kg    = (short*)(ws + (1u << 21));                    // 2 MB
  short* vT2   = (short*)(ws + (2u << 21));                    // 2 MB (k-slot permuted)
  short* pacc  = (short*)(ws + (3u << 21));                    // 16*100*8192*2 = 26.2 MB
  float* lsumg = (float*)(ws + (3u << 21) + 26214400u);        // 16*8192*4 = 512 KB
  float* out   = (float*)d_out;

  proj_qkv<<<dim3(512, 3), 256, 0, stream>>>(x1, x2, Wq, bq, Wk, bk, Wv, bv, qg, kg, vT2);
  attn_fwd<<<512, 256, 0, stream>>>(qg, kg, vT2, pacc, lsumg);
  merge_parts<<<dim3(128, 4), 256, 0, stream>>>(pacc, lsumg, out);
}

// Round 17
// 69.700 us; speedup vs baseline: 3.3470x; 1.1148x over previous
//
#include <hip/hip_runtime.h>
#include <hip/hip_bf16.h>

// Fused attention: q = (x1@Wq+bq)*log2e/10 (bf16), k = x2@Wk+bk, v = x2@Wv+bv.
// out = normalized exp2(q.k) @ v (offset-free softmax; constant cancels in normalization).
// Row-sum via ones-column d=100. kv split 16-way; merge = plain sums (vectorized).
// attn: R12 core (64 q/wave, two-phase counted-vmcnt pipeline). proj: 64 rows/block
// (8 rows/thread) -> W streamed once per 64 rows instead of per 16 (4x less L2 traffic).
// ws: qg 2MB | kg 2MB | vT2 2MB (k-slot permuted) | pacc bf16 26.2MB | lsumg 512KB

typedef __bf16 bf16x8 __attribute__((ext_vector_type(8)));
typedef float  f32x4  __attribute__((ext_vector_type(4)));
typedef short  short8_t __attribute__((ext_vector_type(8)));

#define SM_C 0.14426950408889634f   /* log2(e) / sqrt(100) */

#if __has_builtin(__builtin_amdgcn_global_load_lds)
#define HAVE_GLL 1
#endif

__device__ __forceinline__ void gload16(const short* g, short* l){
#ifdef HAVE_GLL
  __builtin_amdgcn_global_load_lds(
      (__attribute__((address_space(1))) void*)g,
      (__attribute__((address_space(3))) void*)l,
      16, 0, 0);
#else
  *(short8_t*)(l + (threadIdx.x & 63)*8) = *(const short8_t*)(g);
#endif
}

__device__ __forceinline__ short bf(float f){ return __builtin_bit_cast(short, (__bf16)f); }
__device__ __forceinline__ float bf2f(unsigned short v){
  unsigned u = ((unsigned)v) << 16;
  return __builtin_bit_cast(float, u);
}

#define VMW(n) asm volatile("s_waitcnt vmcnt(" #n ")" ::: "memory")
#define BARC do{ __builtin_amdgcn_s_barrier(); asm volatile("" ::: "memory"); }while(0)

// ---------------- projection kernel: 64 rows/block, 8 rows/thread ----------------
__global__ __launch_bounds__(256) void proj_qkv(
    const float* __restrict__ x1, const float* __restrict__ x2,
    const float* __restrict__ Wq, const float* __restrict__ bq,
    const float* __restrict__ Wk, const float* __restrict__ bk,
    const float* __restrict__ Wv, const float* __restrict__ bv,
    short* __restrict__ qg, short* __restrict__ kg, short* __restrict__ vT2)
{
  __shared__ float xs[64][128];              // 32 KB
  __shared__ float vs[64][104];              // 26.6 KB (z==2 only)
  const int z = blockIdx.y;
  const float* x = (z == 0) ? x1 : x2;
  const float* W = (z == 0) ? Wq : (z == 1) ? Wk : Wv;
  const float* b = (z == 0) ? bq : (z == 1) ? bk : bv;
  const int rb = blockIdx.x << 6;            // 64 rows per block
  const int t  = threadIdx.x;
  for (int i = t; i < 8192; i += 256) xs[i >> 7][i & 127] = x[(rb << 7) + i];
  __syncthreads();
  const int rw = t >> 5, cs = t & 31;        // rows rw+8k (k=0..7); cols cs*4..cs*4+3
  float4 a[8];
  if (cs < 25){
    const float4 bb = *(const float4*)(b + (cs << 2));
#pragma unroll
    for (int k = 0; k < 8; ++k) a[k] = bb;
#pragma unroll 4
    for (int i = 0; i < 128; ++i){
      const float4 wv = *(const float4*)(W + i*100 + (cs << 2));
#pragma unroll
      for (int k = 0; k < 8; ++k){
        const float xv = xs[rw + (k << 3)][i];
        a[k].x = fmaf(xv, wv.x, a[k].x);
        a[k].y = fmaf(xv, wv.y, a[k].y);
        a[k].z = fmaf(xv, wv.z, a[k].z);
        a[k].w = fmaf(xv, wv.w, a[k].w);
      }
    }
  }
  if (z < 2){
    short* o = (z == 0) ? qg : kg;
    if (cs < 25){
#pragma unroll
      for (int k = 0; k < 8; ++k){
        float4 av = a[k];
        if (z == 0){   // fold softmax scale into q: scores come out in log2 units
          av.x *= SM_C; av.y *= SM_C; av.z *= SM_C; av.w *= SM_C;
        }
        short4 h;
        h.x = bf(av.x); h.y = bf(av.y); h.z = bf(av.z); h.w = bf(av.w);
        *(short4*)(o + ((rb + rw + (k << 3)) << 7) + (cs << 2)) = h;
      }
    } else {
      short4 hz; hz.x = 0; hz.y = 0; hz.z = 0; hz.w = 0;   // zero-pad cols 100..127
#pragma unroll
      for (int k = 0; k < 8; ++k)
        *(short4*)(o + ((rb + rw + (k << 3)) << 7) + 100 + ((cs - 25) << 2)) = hz;
    }
  } else {
    if (cs < 25){
#pragma unroll
      for (int k = 0; k < 8; ++k){
        const int r = rw + (k << 3);
        vs[r][(cs<<2)+0] = a[k].x; vs[r][(cs<<2)+1] = a[k].y;
        vs[r][(cs<<2)+2] = a[k].z; vs[r][(cs<<2)+3] = a[k].w;
      }
    }
    __syncthreads();
    if (t < 128){
      const int d = t;
      // k-slot-permuted layout, 32-periodic: idx = g*8+j <-> kv = 4g + (j<4 ? j : 12+j)
      // d==100 -> ones column (row-sum extraction); d>100 -> zeros
#pragma unroll
      for (int h = 0; h < 16; ++h){
        const int kv0 = rb + h*4;
        const int o32 = kv0 & 31;
        const int idx = (o32 < 16) ? ((o32 >> 2) << 3) : ((((o32 - 16) >> 2) << 3) + 4);
        const int r0 = kv0 - rb;
        short4 hv;
        hv.x = (d<100)? bf(vs[r0+0][d]) : (d==100 ? (short)0x3F80 : (short)0);
        hv.y = (d<100)? bf(vs[r0+1][d]) : (d==100 ? (short)0x3F80 : (short)0);
        hv.z = (d<100)? bf(vs[r0+2][d]) : (d==100 ? (short)0x3F80 : (short)0);
        hv.w = (d<100)? bf(vs[r0+3][d]) : (d==100 ? (short)0x3F80 : (short)0);
        *(short4*)(vT2 + (d << 13) + (kv0 & ~31) + idx) = hv;
      }
    }
  }
}

// ---------------- flash attention: 512 blocks = 32 qtiles x 16 parts, 64 q/wave ----------------
__global__ __launch_bounds__(256, 2) void attn_fwd(
    const short* __restrict__ qg, const short* __restrict__ kg,
    const short* __restrict__ vT2, short* __restrict__ pacc,
    float* __restrict__ lsumg)
{
  __shared__ alignas(1024) short sK[2][4096];    // 8KB/buf, 16B-block swizzled (XOR r&15)
  __shared__ alignas(1024) short sVT[2][4096];   // 8KB/buf: 64 super-rows (2 d's) x 128B, XOR dd&3
  const int tid  = threadIdx.x;
  const int w    = tid >> 6;
  const int lane = tid & 63;
  const int g    = lane >> 4;
  const int ln   = lane & 15;
  const int orig = blockIdx.x;
  const int part = ((orig & 7) << 1) | ((orig >> 3) & 1);
  const int qt   = orig >> 4;                    // 0..31
  const int qb   = qt*256 + w*64;                // 64 q rows per wave
  const int kvbase = part << 9;                  // 512 kv per part

  // Q fragments (B-operand): lane holds Q[qb+sub*16+ln][ks*32 + g*8 + j], sub=0..3
  bf16x8 qf[4][4];
#pragma unroll
  for (int sub = 0; sub < 4; ++sub)
#pragma unroll
    for (int ks = 0; ks < 4; ++ks)
      qf[sub][ks] = *(const bf16x8*)(qg + (qb + sub*16 + ln)*128 + ks*32 + g*8);

  f32x4 acc[4][7];
#pragma unroll
  for (int sub = 0; sub < 4; ++sub)
#pragma unroll
    for (int db = 0; db < 7; ++db) acc[sub][db] = f32x4{0.f,0.f,0.f,0.f};

  // per-lane staging sources: wave w owns chunks {w, w+4} of K and of V (2+2 loads/tile)
  const short *kA0, *kA1, *vA0, *vA1;
  {
    const int r0 = (w << 2)       + (lane >> 4);
    const int r1 = ((w + 4) << 2) + (lane >> 4);
    kA0 = kg + (kvbase + r0)*128 + (((lane & 15) ^ (r0 & 15)) << 3);
    kA1 = kg + (kvbase + r1)*128 + (((lane & 15) ^ (r1 & 15)) << 3);
    const int a0 = (w << 10) + (lane << 4);
    const int a1 = ((w + 4) << 10) + (lane << 4);
    const int dd0 = a0 >> 7, d0 = (dd0 << 1) + ((a0 >> 6) & 1), gs0 = ((a0 >> 4) & 3) ^ (dd0 & 3);
    const int dd1 = a1 >> 7, d1 = (dd1 << 1) + ((a1 >> 6) & 1), gs1 = ((a1 >> 4) & 3) ^ (dd1 & 3);
    vA0 = vT2 + d0*8192 + kvbase + (gs0 << 3);
    vA1 = vT2 + d1*8192 + kvbase + (gs1 << 3);
  }

  auto stageK = [&](int tt){
    short* dst = sK[tt & 1];
    const int off = tt << 12;                    // 32 kv rows * 128 shorts
    gload16(kA0 + off, dst + (w << 9));
    gload16(kA1 + off, dst + ((w + 4) << 9));
  };
  auto stageV = [&](int tt){
    short* dst = sVT[tt & 1];
    const int off = tt << 5;                     // 32 kv shorts (contiguous kv dim)
    gload16(vA0 + off, dst + (w << 9));
    gload16(vA1 + off, dst + ((w + 4) << 9));
  };

  bf16x8 pb[4];                                  // P fragments, live phaseA -> phaseB

  auto phaseA = [&](int buf, int sv){            // QK^T + exp2 (reads K[buf])
    if (sv >= 0) stageV(sv);
    const short* sKc = sK[buf];
    f32x4 st[4][2];
#pragma unroll
    for (int sub = 0; sub < 4; ++sub){
      st[sub][0] = f32x4{0.f,0.f,0.f,0.f};
      st[sub][1] = f32x4{0.f,0.f,0.f,0.f};
    }
    __builtin_amdgcn_s_setprio(1);
#pragma unroll
    for (int s = 0; s < 2; ++s){
      const int rbase = (s*16 + ln) << 7;
#pragma unroll
      for (int ks = 0; ks < 4; ++ks){
        bf16x8 kf = *(const bf16x8*)(sKc + rbase + ((((ks << 2) + g) ^ ln) << 3));
        st[0][s] = __builtin_amdgcn_mfma_f32_16x16x32_bf16(kf, qf[0][ks], st[0][s], 0, 0, 0);
        st[1][s] = __builtin_amdgcn_mfma_f32_16x16x32_bf16(kf, qf[1][ks], st[1][s], 0, 0, 0);
        st[2][s] = __builtin_amdgcn_mfma_f32_16x16x32_bf16(kf, qf[2][ks], st[2][s], 0, 0, 0);
        st[3][s] = __builtin_amdgcn_mfma_f32_16x16x32_bf16(kf, qf[3][ks], st[3][s], 0, 0, 0);
      }
    }
    __builtin_amdgcn_s_setprio(0);
#pragma unroll
    for (int sub = 0; sub < 4; ++sub){
      bf16x8 pv;
#pragma unroll
      for (int r = 0; r < 4; ++r){
        pv[r]     = (__bf16)exp2f(st[sub][0][r]);  // k-slot j<4  -> kv = 4g+j
        pv[4 + r] = (__bf16)exp2f(st[sub][1][r]);  // k-slot j>=4 -> kv = 16+4g+(j-4)
      }
      pb[sub] = pv;
    }
  };

  auto phaseB = [&](int buf, int sk){            // PV (reads V[buf])
    if (sk >= 0) stageK(sk);
    const short* sVc = sVT[buf];
    __builtin_amdgcn_s_setprio(1);
#pragma unroll
    for (int db = 0; db < 7; ++db){
      const int row = db*16 + ln;
      const int dd  = row >> 1;
      bf16x8 vf = *(const bf16x8*)(sVc + (dd << 6) + ((row & 1) << 5) + ((g ^ (dd & 3)) << 3));
      acc[0][db] = __builtin_amdgcn_mfma_f32_16x16x32_bf16(vf, pb[0], acc[0][db], 0, 0, 0);
      acc[1][db] = __builtin_amdgcn_mfma_f32_16x16x32_bf16(vf, pb[1], acc[1][db], 0, 0, 0);
      acc[2][db] = __builtin_amdgcn_mfma_f32_16x16x32_bf16(vf, pb[2], acc[2][db], 0, 0, 0);
      acc[3][db] = __builtin_amdgcn_mfma_f32_16x16x32_bf16(vf, pb[3], acc[3][db], 0, 0, 0);
    }
    __builtin_amdgcn_s_setprio(0);
  };

  // prologue: 6 loads in flight (K0,V0,K1); R8 schedule
  stageK(0); stageV(0); stageK(1);
  for (int t = 0; t < 14; ++t){
    VMW(4); BARC; phaseA(t & 1, t + 1);          // K(t) ready; V(t),K(t+1) stay in flight
    VMW(4); BARC; phaseB(t & 1, t + 2);          // V(t) ready; K(t+1),V(t+1) in flight
  }
  VMW(4); BARC; phaseA(0, 15);                   // t=14
  VMW(4); BARC; phaseB(0, -1);
  VMW(2); BARC; phaseA(1, -1);                   // t=15
  VMW(0); BARC; phaseB(1, -1);

  // ---- epilogue: bf16 partials (d<100) + fp32 row-sums from ones-column (d=100) ----
#pragma unroll
  for (int sub = 0; sub < 4; ++sub){
#pragma unroll
    for (int db = 0; db < 7; ++db)
#pragma unroll
      for (int r = 0; r < 4; ++r){
        const int d = db*16 + g*4 + r;
        if (d < 100)
          pacc[((part*100 + d) << 13) + qb + sub*16 + ln] = bf(acc[sub][db][r]);
      }
    if (g == 1)  // acc[sub][6][0] is d = 96+4 = 100 -> row sum
      lsumg[(part << 13) + qb + sub*16 + ln] = acc[sub][6][0];
  }
}

// ---------------- merge kernel: 512 blocks (128 q-blocks x 4 d-chunks), short8 loads ----------------
__global__ __launch_bounds__(256) void merge_parts(
    const short* __restrict__ pacc, const float* __restrict__ lsumg,
    float* __restrict__ out)
{
  __shared__ float ol[64][26];
  const int t   = threadIdx.x;
  const int qo8 = (t & 7) << 3;          // q octet offset 0..56
  const int dt  = t >> 3;                // 0..31 (25 used)
  const int qb  = blockIdx.x << 6;       // 64 q rows
  const int db  = blockIdx.y * 25;       // 25 d cols
  const int q0  = qb + qo8;

  // row sums for this thread's 8 q's (same for all dt -> L1 broadcast)
  float L8[8];
#pragma unroll
  for (int j = 0; j < 8; ++j) L8[j] = 0.f;
#pragma unroll
  for (int p = 0; p < 16; ++p){
    const float4 a = *(const float4*)(lsumg + (p << 13) + q0);
    const float4 c = *(const float4*)(lsumg + (p << 13) + q0 + 4);
    L8[0]+=a.x; L8[1]+=a.y; L8[2]+=a.z; L8[3]+=a.w;
    L8[4]+=c.x; L8[5]+=c.y; L8[6]+=c.z; L8[7]+=c.w;
  }

  if (dt < 25){
    const int d = db + dt;
    float s8[8];
#pragma unroll
    for (int j = 0; j < 8; ++j) s8[j] = 0.f;
#pragma unroll
    for (int p = 0; p < 16; ++p){
      short8_t v = *(const short8_t*)(pacc + ((p*100 + d) << 13) + q0);
#pragma unroll
      for (int j = 0; j < 8; ++j) s8[j] += bf2f((unsigned short)v[j]);
    }
#pragma unroll
    for (int j = 0; j < 8; ++j) ol[qo8 + j][dt] = s8[j] / L8[j];
  }
  __syncthreads();
  for (int idx = t; idx < 1600; idx += 256){
    const int q2 = idx / 25, d2 = idx - q2*25;
    out[(qb + q2)*100 + db + d2] = ol[q2][d2];
  }
}

// ---------------- launcher ----------------
extern "C" void kernel_launch(void* const* d_in, const int* in_sizes, int n_in,
                              void* d_out, int out_size, void* d_ws, size_t ws_size,
                              hipStream_t stream)
{
  const float* x1 = (const float*)d_in[0];
  const float* x2 = (const float*)d_in[1];
  const float* Wq = (const float*)d_in[2];
  const float* bq = (const float*)d_in[3];
  const float* Wk = (const float*)d_in[4];
  const float* bk = (const float*)d_in[5];
  const float* Wv = (const float*)d_in[6];
  const float* bv = (const float*)d_in[7];
  char* ws = (char*)d_ws;
  short* qg    = (short*)ws;                                   // 2 MB
  short* kg    = (short*)(ws + (1u << 21));                    // 2 MB
  short* vT2   = (short*)(ws + (2u << 21));                    // 2 MB (k-slot permuted)
  short* pacc  = (short*)(ws + (3u << 21));                    // 16*100*8192*2 = 26.2 MB
  float* lsumg = (float*)(ws + (3u << 21) + 26214400u);        // 16*8192*4 = 512 KB
  float* out   = (float*)d_out;

  proj_qkv<<<dim3(128, 3), 256, 0, stream>>>(x1, x2, Wq, bq, Wk, bk, Wv, bv, qg, kg, vT2);
  attn_fwd<<<512, 256, 0, stream>>>(qg, kg, vT2, pacc, lsumg);
  merge_parts<<<dim3(128, 4), 256, 0, stream>>>(pacc, lsumg, out);
}